// Round 7
// baseline (212.942 us; speedup 1.0000x reference)
//
#include <hip/hip_runtime.h>

#define B_DIM 8
#define N_DIM 2048
#define C_DIM 256
#define K_SEL 1024

typedef __attribute__((ext_vector_type(8))) short short8;
typedef __attribute__((ext_vector_type(4))) float f32x4;

__device__ __forceinline__ unsigned int bf16rne(float x) {
  unsigned int u = __float_as_uint(x);
  return (u + 0x7fffu + ((u >> 16) & 1u)) >> 16;
}

// ---------------- LayerNorm, numpy-bit-exact, LDS-staged (v6 widened, verified) ----------------
__global__ __launch_bounds__(256) void ln_lds(const float* __restrict__ feat,
    const float* __restrict__ gamma, const float* __restrict__ beta,
    float* __restrict__ fbuf) {
  __shared__ float tile[256 * 64];   // 64 KB
  __shared__ float murs[128];        // mu[0:64], rs[64:128]
  const int t = threadIdx.x;
  const int m0 = blockIdx.x << 6;
  const int b = m0 >> 11, n0 = m0 & 2047;

  const int cg = t >> 4, nl4 = (t & 15) << 2;   // cg in 0..15
  for (int pass = 0; pass < 16; ++pass) {
    const int c = (pass << 4) + cg;
    const float4 v = *(const float4*)(feat + (((long)((b << 8) + c)) << 11) + n0 + nl4);
    const int sw = c & 31;
    float* row = tile + (c << 6);
    row[(nl4 + 0) ^ sw] = v.x; row[(nl4 + 1) ^ sw] = v.y;
    row[(nl4 + 2) ^ sw] = v.z; row[(nl4 + 3) ^ sw] = v.w;
  }
  __syncthreads();

  if (t < 64) {
    // mean: sequential ascending single chain (numpy strided-axis outer reduction)
    float acc = tile[t];
    for (int c = 1; c < 256; ++c) acc = __fadd_rn(acc, tile[(c << 6) + (t ^ (c & 31))]);
    const float mu = __fdiv_rn(acc, 256.0f);

    // var: numpy pairwise (2 halves x 8 accumulators) on contiguous (x-mu)^2
    float pw[2];
#pragma unroll
    for (int blk = 0; blk < 2; ++blk) {
      const int c0 = blk << 7;
      float r8[8];
#pragma unroll
      for (int j = 0; j < 8; ++j) {
        float d = __fsub_rn(tile[((c0 + j) << 6) + (t ^ ((c0 + j) & 31))], mu);
        r8[j] = __fmul_rn(d, d);
      }
      for (int i = 8; i < 128; i += 8) {
#pragma unroll
        for (int j = 0; j < 8; ++j) {
          const int c = c0 + i + j;
          float d = __fsub_rn(tile[(c << 6) + (t ^ (c & 31))], mu);
          r8[j] = __fadd_rn(r8[j], __fmul_rn(d, d));
        }
      }
      pw[blk] = __fadd_rn(__fadd_rn(__fadd_rn(r8[0], r8[1]), __fadd_rn(r8[2], r8[3])),
                          __fadd_rn(__fadd_rn(r8[4], r8[5]), __fadd_rn(r8[6], r8[7])));
    }
    const float var = __fdiv_rn(__fadd_rn(pw[0], pw[1]), 256.0f);
    const float rs = __fdiv_rn(1.0f, __fsqrt_rn(__fadd_rn(var, 1e-6f)));
    murs[t] = mu;
    murs[64 + t] = rs;
  }
  __syncthreads();

  const int tc = t & 63, rg = t >> 6;
  const int c0 = tc << 2;
  const float4 g4 = *(const float4*)(gamma + c0);
  const float4 b4 = *(const float4*)(beta + c0);
  const float ga[4] = {g4.x, g4.y, g4.z, g4.w};
  const float be[4] = {b4.x, b4.y, b4.z, b4.w};
  for (int rr = 0; rr < 16; ++rr) {
    const int r = (rg << 4) + rr;
    const float mu_r = murs[r];
    const float rs_r = murs[64 + r];
    float4 o;
    float ov[4];
#pragma unroll
    for (int q = 0; q < 4; ++q) {
      const int c = c0 + q;
      const float x = tile[(c << 6) + (r ^ (c & 31))];
      ov[q] = __fadd_rn(__fmul_rn(__fmul_rn(__fsub_rn(x, mu_r), rs_r), ga[q]), be[q]);
    }
    o.x = ov[0]; o.y = ov[1]; o.z = ov[2]; o.w = ov[3];
    *(float4*)(fbuf + (((long)(m0 + r)) << 8) + c0) = o;
  }
}

// ---------------- fused down-GEMM + w-chain, 512 threads (bit-exact chains) ----------------
// v8: readlane-A (v7, verified bit-exact, 8 VGPRs) + double-buffered 32-row B chunks.
// v7 showed LDS issue was NOT the limit (288->96 cyc/kk, same 49us): the lock-step
// stage->barrier->compute->barrier x32 at 1 block/CU exposes a full global round-trip
// per 16-k step. v8: per 32-k chunk, issue next B (4 float4 regs) + next A BEFORE the
// 32-kk compute (~2560 cyc/wave, covers HBM latency), write regs->LDS after compute,
// ONE barrier per chunk (8 total, was 32). Live set ~85 VGPR < 128 cap -> no spill
// (v2/v4/v5 spilled only because their A-files were 64-128 regs; this A is 8).
// Buffer safety: Bn writes at chunk ch happen after the barrier ending ch-1, which is
// after all reads of that buffer. FMA chain per (m,c) stays ascending-k single chain
// -> bit-exact w (top-k safe). B staging lane map = v5/v7 conflict-free (verified 0).
__global__ void __launch_bounds__(512) wgemm_w(
    const float* __restrict__ A, const float* __restrict__ Wd1,
    const float* __restrict__ bd1, const float* __restrict__ Wd2,
    const float* __restrict__ bd2, float* __restrict__ wkey) {
  __shared__ __align__(16) char smem[66560];
  float* Bs0 = (float*)smem;                   // 32x260 f32 = 33280 B
  float* Bs1 = (float*)(smem + 33280);         // 33280 B (double buffer)
  float* H = (float*)smem;                     // 256x64 f32 = 64 KB (epilogue alias)

  const int t = threadIdx.x;
  const int m0 = blockIdx.x << 6;
  const int rowT = t >> 6, colT = t & 63;
  const int lane = t & 63;
  const int bk = t >> 5, bl4 = (t & 31) << 2;  // B staging: lane-consecutive float4s
  // wave's A slab: lane l covers row (rowT*8 + (l&7)), k-offset (l>>3)*4 within chunk
  const float* aload = A + ((long)(m0 + (rowT << 3) + (lane & 7)) << 8) + ((lane >> 3) << 2);

  float acc[8][4] = {};

  // prologue: stage B chunk 0 (rows 0..31) into Bs0; load A chunk 0
  {
    const float* brow0 = Wd1 + (bk << 8);
    const float* brow1 = Wd1 + ((bk + 16) << 8);
    *(float4*)(Bs0 + bk * 260 + bl4)              = *(const float4*)(brow0 + bl4);
    *(float4*)(Bs0 + bk * 260 + bl4 + 128)        = *(const float4*)(brow0 + bl4 + 128);
    *(float4*)(Bs0 + (bk + 16) * 260 + bl4)       = *(const float4*)(brow1 + bl4);
    *(float4*)(Bs0 + (bk + 16) * 260 + bl4 + 128) = *(const float4*)(brow1 + bl4 + 128);
  }
  float4 ac = *(const float4*)(aload);
  __syncthreads();

  const float* Bc = Bs0;
  float* Bn = Bs1;
  for (int ch = 0; ch < 8; ++ch) {
    // issue next-chunk loads first (wrap at ch=7: loads chunk 0 again, discarded)
    const int cn = (ch + 1) & 7;
    float4 r0, r1, r2, r3;
    {
      const float* brow0 = Wd1 + (((cn << 5) + bk) << 8);
      const float* brow1 = Wd1 + (((cn << 5) + bk + 16) << 8);
      r0 = *(const float4*)(brow0 + bl4);
      r1 = *(const float4*)(brow0 + bl4 + 128);
      r2 = *(const float4*)(brow1 + bl4);
      r3 = *(const float4*)(brow1 + bl4 + 128);
    }
    const float4 an = *(const float4*)(aload + (cn << 5));

    // compute 32 kk from Bc (k ascending: single FMA chain per (m,c))
#pragma unroll
    for (int kk = 0; kk < 32; ++kk) {
      const float4 b = *(const float4*)(Bc + kk * 260 + (colT << 2));
      const float bbv[4] = {b.x, b.y, b.z, b.w};
      const float av_src = (kk & 3) == 0 ? ac.x : (kk & 3) == 1 ? ac.y
                         : (kk & 3) == 2 ? ac.z : ac.w;
#pragma unroll
      for (int i = 0; i < 8; ++i) {
        const float aval = __uint_as_float(__builtin_amdgcn_readlane(
            __float_as_uint(av_src), ((kk >> 2) << 3) + i));
#pragma unroll
        for (int j = 0; j < 4; ++j)
          acc[i][j] = __fmaf_rn(aval, bbv[j], acc[i][j]);
      }
    }

    if (ch < 7) {
      // write prefetched chunk into the other buffer (compiler inserts vmcnt wait;
      // loads were issued ~2560 cyc ago -> latency hidden)
      *(float4*)(Bn + bk * 260 + bl4)              = r0;
      *(float4*)(Bn + bk * 260 + bl4 + 128)        = r1;
      *(float4*)(Bn + (bk + 16) * 260 + bl4)       = r2;
      *(float4*)(Bn + (bk + 16) * 260 + bl4 + 128) = r3;
      ac = an;
    }
    __syncthreads();   // one barrier per chunk; final one guards the H alias below
    float* tmp = (float*)Bc; Bc = Bn; Bn = tmp;
  }

  // epilogue: bias + relu -> H[c][m] swizzled (unchanged, verified)
  const float4 bd = *(const float4*)(bd1 + (colT << 2));
  const float ba[4] = {bd.x, bd.y, bd.z, bd.w};
#pragma unroll
  for (int i = 0; i < 8; ++i) {
    const int m = (rowT << 3) + i;
#pragma unroll
    for (int j = 0; j < 4; ++j) {
      const int c = (colT << 2) + j;
      H[(c << 6) + (m ^ ((c >> 2) & 31))] = fmaxf(__fadd_rn(acc[i][j], ba[j]), 0.0f);
    }
  }
  __syncthreads();

  // w-chain: ascending-c single FMA chain; key = (w+bd2)/0.1f (unchanged, verified)
  if (t < 64) {
    float wa = 0.0f;
    for (int c = 0; c < 256; ++c)
      wa = __fmaf_rn(H[(c << 6) + (t ^ ((c >> 2) & 31))], Wd2[c], wa);
    const float w = __fadd_rn(wa, bd2[0]);
    wkey[m0 + t] = __fdiv_rn(w, 0.1f);
  }
}

// ---------------- per-batch top-K: u64-packed bitonic (key desc, tie: lower idx) ----------------
__global__ void __launch_bounds__(1024) topk_kernel(
    const float* __restrict__ wv, const float* __restrict__ xyzs,
    int* __restrict__ idx_out, float* __restrict__ out_xyz,
    float* __restrict__ out_idx) {
  __shared__ unsigned long long vals[2048];
  const int b = blockIdx.x, t = threadIdx.x;
#pragma unroll
  for (int h = 0; h < 2; ++h) {
    const int i = (h << 10) + t;
    const unsigned int u = __float_as_uint(wv[(b << 11) + i]);
    const unsigned int up = ((int)u < 0) ? ~u : (u | 0x80000000u);
    vals[i] = (((unsigned long long)(~up)) << 32) | (unsigned int)i;
  }
  __syncthreads();
  for (int k = 2; k <= 2048; k <<= 1) {
    for (int j = k >> 1; j > 0; j >>= 1) {
      for (int half = 0; half < 2; ++half) {
        const int i = (half << 10) | t;
        const int ixj = i ^ j;
        if (ixj > i) {
          const unsigned long long vi = vals[i], vj = vals[ixj];
          const bool up = ((i & k) == 0);
          if ((vi > vj) == up) { vals[i] = vj; vals[ixj] = vi; }
        }
      }
      __syncthreads();
    }
  }
  const int sel = (int)(vals[t] & 0xffffffffu);
  idx_out[(b << 10) + t] = sel;
  out_idx[(b << 10) + t] = (float)sel;
  const long o = ((long)((b << 10) + t)) * 3;
  const long s3 = ((long)((b << 11) + sel)) * 3;
  out_xyz[o] = xyzs[s3]; out_xyz[o + 1] = xyzs[s3 + 1]; out_xyz[o + 2] = xyzs[s3 + 2];
}

// ---------------- weight prep (merged): W (256x256 f32) -> P bf16 slabs [kc][n][32] ----------------
__global__ __launch_bounds__(256) void prep_w2(const float* __restrict__ W1,
    const float* __restrict__ W2, unsigned short* __restrict__ P1,
    unsigned short* __restrict__ P2) {
  const int g = blockIdx.x;
  const float* W = (g < 8) ? W1 : W2;
  unsigned short* P = (g < 8) ? P1 : P2;
  const int kc = g & 7, n = threadIdx.x;
  unsigned int packed[16];
#pragma unroll
  for (int i = 0; i < 16; ++i) {
    const float a = W[(((kc << 5) + 2 * i) << 8) + n];
    const float bq = W[(((kc << 5) + 2 * i + 1) << 8) + n];
    packed[i] = bf16rne(a) | (bf16rne(bq) << 16);
  }
  uint4* dst = (uint4*)(P + (((kc << 8) + n) << 5));
#pragma unroll
  for (int q = 0; q < 4; ++q)
    dst[q] = make_uint4(packed[4 * q], packed[4 * q + 1], packed[4 * q + 2], packed[4 * q + 3]);
}

// ---------------- fused up-branch: gather -> bf16 MFMA GEMM1(relu) -> GEMM2 -> transposed out ----------------
#define APITCH 264
#define BPITCH 40
__global__ void __launch_bounds__(256) up_mfma(
    const float* __restrict__ fbuf, const int* __restrict__ idxm,
    const unsigned short* __restrict__ Wu1P, const float* __restrict__ bu1,
    const unsigned short* __restrict__ Wu2P, const float* __restrict__ bu2,
    float* __restrict__ out_feat) {
  __shared__ __align__(16) char smem[64 * APITCH * 2 + 256 * BPITCH * 2 + 2048];
  unsigned short* As = (unsigned short*)smem;                       // 33792 B (later Hs)
  unsigned short* Bs = (unsigned short*)(smem + 64 * APITCH * 2);   // 20480 B (later T)
  float* bias1 = (float*)(smem + 64 * APITCH * 2 + 256 * BPITCH * 2);
  float* bias2 = bias1 + 256;
  float* T = (float*)(smem + 64 * APITCH * 2);                      // 64x66 f32 = 16896 B

  const int t = threadIdx.x;
  const int m0 = blockIdx.x << 6;
  const int quad = (t >> 4) & 3, ln = t & 15, w = t >> 6;

  bias1[t] = bu1[t];
  bias2[t] = bu2[t];

  // gather + cvt: As[r][c] bf16, r = t&63, cols (t>>6)*64..+63
  {
    const int r = t & 63, cseg = t >> 6;
    const int m = m0 + r;
    const long srow = (long)(((m >> 10) << 11) + idxm[m]) << 8;
    const float* src = fbuf + srow + (cseg << 6);
    unsigned short* dst = As + r * APITCH + (cseg << 6);
#pragma unroll
    for (int u = 0; u < 16; ++u) {
      const float4 v = *(const float4*)(src + (u << 2));
      const unsigned int lo = bf16rne(v.x) | (bf16rne(v.y) << 16);
      const unsigned int hi = bf16rne(v.z) | (bf16rne(v.w) << 16);
      *(uint2*)(dst + (u << 2)) = make_uint2(lo, hi);
    }
  }

  f32x4 acc[16];
#pragma unroll
  for (int i = 0; i < 16; ++i) acc[i] = (f32x4){0.f, 0.f, 0.f, 0.f};

  // ---- GEMM1: hu = gathered_f @ Wu1 ----
  for (int kc = 0; kc < 8; ++kc) {
    __syncthreads();
    const uint4* sb = (const uint4*)(Wu1P + (((kc << 8) + t) << 5));
    uint4* db = (uint4*)(Bs + t * BPITCH);
    db[0] = sb[0]; db[1] = sb[1]; db[2] = sb[2]; db[3] = sb[3];
    __syncthreads();
    const short8 a = *(const short8*)(As + ((w << 4) + ln) * APITCH + (kc << 5) + (quad << 3));
#pragma unroll
    for (int nt = 0; nt < 16; ++nt) {
      const short8 b = *(const short8*)(Bs + ((nt << 4) + ln) * BPITCH + (quad << 3));
      acc[nt] = __builtin_amdgcn_mfma_f32_16x16x32_bf16(a, b, acc[nt], 0, 0, 0);
    }
  }

  // ---- relu + bias -> Hs (alias As) ----
  __syncthreads();
  unsigned short* Hs = As;
#pragma unroll
  for (int nt = 0; nt < 16; ++nt) {
    const int c = (nt << 4) + ln;
    const float bb = bias1[c];
#pragma unroll
    for (int rr = 0; rr < 4; ++rr) {
      const float h = fmaxf(acc[nt][rr] + bb, 0.0f);
      Hs[((w << 4) + (quad << 2) + rr) * APITCH + c] = (unsigned short)bf16rne(h);
    }
  }
#pragma unroll
  for (int i = 0; i < 16; ++i) acc[i] = (f32x4){0.f, 0.f, 0.f, 0.f};

  // ---- GEMM2: nf = hu @ Wu2 ----
  for (int kc = 0; kc < 8; ++kc) {
    __syncthreads();
    const uint4* sb = (const uint4*)(Wu2P + (((kc << 8) + t) << 5));
    uint4* db = (uint4*)(Bs + t * BPITCH);
    db[0] = sb[0]; db[1] = sb[1]; db[2] = sb[2]; db[3] = sb[3];
    __syncthreads();
    const short8 a = *(const short8*)(Hs + ((w << 4) + ln) * APITCH + (kc << 5) + (quad << 3));
#pragma unroll
    for (int nt = 0; nt < 16; ++nt) {
      const short8 b = *(const short8*)(Bs + ((nt << 4) + ln) * BPITCH + (quad << 3));
      acc[nt] = __builtin_amdgcn_mfma_f32_16x16x32_bf16(a, b, acc[nt], 0, 0, 0);
    }
  }

  // ---- epilogue: +bu2, transpose via LDS, write out_feat (B,C,K) coalesced ----
  const int bb = m0 >> 10, kbase = m0 & 1023;
  for (int ci = 0; ci < 4; ++ci) {
    __syncthreads();
#pragma unroll
    for (int q = 0; q < 4; ++q) {
      const int nt = (ci << 2) + q;
      const int cloc = (q << 4) + ln;
      const float b2 = bias2[(nt << 4) + ln];
#pragma unroll
      for (int rr = 0; rr < 4; ++rr)
        T[cloc * 66 + ((w << 4) + (quad << 2) + rr)] = acc[nt][rr] + b2;
    }
    __syncthreads();
#pragma unroll
    for (int p = 0; p < 16; ++p) {
      const int cl = (p << 2) + (t >> 6);
      const int m = t & 63;
      out_feat[((long)((bb << 8) + (ci << 6) + cl) << 10) + kbase + m] = T[cl * 66 + m];
    }
  }
}

extern "C" void kernel_launch(void* const* d_in, const int* in_sizes, int n_in,
                              void* d_out, int out_size, void* d_ws, size_t ws_size,
                              hipStream_t stream) {
  const float* xyzs     = (const float*)d_in[0];
  const float* features = (const float*)d_in[1];
  const float* ln_gamma = (const float*)d_in[2];
  const float* ln_beta  = (const float*)d_in[3];
  const float* Wu1      = (const float*)d_in[4];
  const float* bu1      = (const float*)d_in[5];
  const float* Wu2      = (const float*)d_in[6];
  const float* bu2      = (const float*)d_in[7];
  const float* Wd1      = (const float*)d_in[8];
  const float* bd1      = (const float*)d_in[9];
  const float* Wd2      = (const float*)d_in[10];
  const float* bd2      = (const float*)d_in[11];

  char* ws = (char*)d_ws;
  float* fbuf = (float*)ws;                              // 16 MB
  unsigned short* Wu1P = (unsigned short*)(ws + 33554432);  // 128 KB bf16 slabs
  unsigned short* Wu2P = (unsigned short*)(ws + 33685504);  // 128 KB
  float* wv   = (float*)(ws + 50331648);                 // 16384 f32
  int*   idx  = (int*)(ws + 50397184);                   // 8192 i32

  float* out_xyz  = (float*)d_out;            // (8,1024,3)
  float* out_feat = out_xyz + 24576;          // (8,256,1024)
  float* out_idx  = out_feat + 2097152;       // (8,1024)

  prep_w2<<<16, 256, 0, stream>>>(Wu1, Wu2, Wu1P, Wu2P);
  ln_lds<<<256, 256, 0, stream>>>(features, ln_gamma, ln_beta, fbuf);
  wgemm_w<<<256, 512, 0, stream>>>(fbuf, Wd1, bd1, Wd2, bd2, wv);
  topk_kernel<<<8, 1024, 0, stream>>>(wv, xyzs, idx, out_xyz, out_idx);
  up_mfma<<<128, 256, 0, stream>>>(fbuf, idx, Wu1P, bu1, Wu2P, bu2, out_feat);
}

// Round 8
// 184.151 us; speedup vs baseline: 1.1563x; 1.1563x over previous
//
#include <hip/hip_runtime.h>

#define B_DIM 8
#define N_DIM 2048
#define C_DIM 256
#define K_SEL 1024

typedef __attribute__((ext_vector_type(8))) short short8;
typedef __attribute__((ext_vector_type(4))) float f32x4;

__device__ __forceinline__ unsigned int bf16rne(float x) {
  unsigned int u = __float_as_uint(x);
  return (u + 0x7fffu + ((u >> 16) & 1u)) >> 16;
}

// ---------------- FUSED LayerNorm + down-GEMM + w-chain, 512 threads ----------------
// v9: ln_lds and wgemm_w operate on the SAME 64 rows per block (both grid 256,
// m0 = blockIdx*64). Fused: stage raw features once (swizzled tile, 64 KB), compute
// mu/rs (numpy-bit-exact chains, verbatim), write fbuf (needed by up_mfma), then run
// the round-0 K-loop with As staged FROM THE TILE with normalize folded in (identical
// __f*_rn expression -> bit-identical A values to the fbuf path -> w bit-exact, top-k
// safe). Kills the 16MB fbuf re-read (v7 showed the per-chunk A global round-trip is
// the wgemm stall; L3-miss FETCH was 9.3MB/dispatch) + one launch + duplicate staging.
// K-loop / H epilogue / w-chain are round-0 VERBATIM (7 restructure attempts v2-v8 all
// lost to spill/scalarization/issue-inflation; the structure stays).
__global__ void __launch_bounds__(512) ln_wgemm(
    const float* __restrict__ feat, const float* __restrict__ gamma,
    const float* __restrict__ beta, float* __restrict__ fbuf,
    const float* __restrict__ Wd1, const float* __restrict__ bd1,
    const float* __restrict__ Wd2, const float* __restrict__ bd2,
    float* __restrict__ wkey) {
  __shared__ __align__(16) float tile[256 * 64];       // 64 KB raw x, [c][m ^ (c&31)]
  __shared__ __align__(16) char smem2[4352 + 16640];   // As 16x68x4 | Bs 16x260x4
  __shared__ float murs[128];                          // mu[0:64], rs[64:128]
  __shared__ float gb[512];                            // gamma[0:256], beta[256:512]
  float (*As)[68] = (float (*)[68])smem2;
  float (*Bs)[260] = (float (*)[260])(smem2 + 4352);
  float* H = tile;                                     // epilogue alias (tile dead then)

  const int t = threadIdx.x;
  const int m0 = blockIdx.x << 6;
  const int b = m0 >> 11, n0 = m0 & 2047;

  if (t < 256) gb[t] = gamma[t];
  else gb[t] = beta[t - 256];

  // phase 1: stage raw features (v6 pattern, 512 threads, 8 passes)
  const int cg = t >> 4, nl4 = (t & 15) << 2;          // cg 0..31
  for (int pass = 0; pass < 8; ++pass) {
    const int c = (pass << 5) + cg;
    const float4 v = *(const float4*)(feat + (((long)((b << 8) + c)) << 11) + n0 + nl4);
    const int sw = c & 31;
    float* row = tile + (c << 6);
    row[(nl4 + 0) ^ sw] = v.x; row[(nl4 + 1) ^ sw] = v.y;
    row[(nl4 + 2) ^ sw] = v.z; row[(nl4 + 3) ^ sw] = v.w;
  }
  __syncthreads();

  // phase 2: mean/var, numpy-bit-exact (verbatim from verified ln_lds), t<64
  if (t < 64) {
    float acc = tile[t];
    for (int c = 1; c < 256; ++c) acc = __fadd_rn(acc, tile[(c << 6) + (t ^ (c & 31))]);
    const float mu = __fdiv_rn(acc, 256.0f);

    float pw[2];
#pragma unroll
    for (int blk = 0; blk < 2; ++blk) {
      const int c0 = blk << 7;
      float r8[8];
#pragma unroll
      for (int j = 0; j < 8; ++j) {
        float d = __fsub_rn(tile[((c0 + j) << 6) + (t ^ ((c0 + j) & 31))], mu);
        r8[j] = __fmul_rn(d, d);
      }
      for (int i = 8; i < 128; i += 8) {
#pragma unroll
        for (int j = 0; j < 8; ++j) {
          const int c = c0 + i + j;
          float d = __fsub_rn(tile[(c << 6) + (t ^ (c & 31))], mu);
          r8[j] = __fadd_rn(r8[j], __fmul_rn(d, d));
        }
      }
      pw[blk] = __fadd_rn(__fadd_rn(__fadd_rn(r8[0], r8[1]), __fadd_rn(r8[2], r8[3])),
                          __fadd_rn(__fadd_rn(r8[4], r8[5]), __fadd_rn(r8[6], r8[7])));
    }
    const float var = __fdiv_rn(__fadd_rn(pw[0], pw[1]), 256.0f);
    const float rs = __fdiv_rn(1.0f, __fsqrt_rn(__fadd_rn(var, 1e-6f)));
    murs[t] = mu;
    murs[64 + t] = rs;
  }
  __syncthreads();

  // phase 3: write fbuf (512 threads, 8 rows each, float4 stores; same expression)
  {
    const int tc = t & 63, rg = t >> 6;
    const int c0 = tc << 2;
    const float4 g4 = *(const float4*)(gamma + c0);
    const float4 b4 = *(const float4*)(beta + c0);
    const float ga[4] = {g4.x, g4.y, g4.z, g4.w};
    const float be[4] = {b4.x, b4.y, b4.z, b4.w};
    for (int rr = 0; rr < 8; ++rr) {
      const int r = (rg << 3) + rr;
      const float mu_r = murs[r];
      const float rs_r = murs[64 + r];
      float ov[4];
#pragma unroll
      for (int q = 0; q < 4; ++q) {
        const int c = c0 + q;
        const float x = tile[(c << 6) + (r ^ (c & 31))];
        ov[q] = __fadd_rn(__fmul_rn(__fmul_rn(__fsub_rn(x, mu_r), rs_r), ga[q]), be[q]);
      }
      float4 o; o.x = ov[0]; o.y = ov[1]; o.z = ov[2]; o.w = ov[3];
      *(float4*)(fbuf + (((long)(m0 + r)) << 8) + c0) = o;
    }
  }
  // no barrier needed: everything below only READS tile/murs/gb until the K-loop's own

  // phase 4: round-0 K-loop; As staged from tile with normalize folded in
  const int rowT = t >> 6, colT = t & 63;
  const int ar = t >> 2, ak = (t & 3) << 2;            // As stagers: t<256
  const int bk = t >> 5, bc = (t & 31) << 3;           // Bs stagers: all 512
  float mu_a = 0.0f, rs_a = 0.0f;
  if (t < 256) { mu_a = murs[ar]; rs_a = murs[64 + ar]; }
  float acc[8][4] = {};

  for (int k0 = 0; k0 < 256; k0 += 16) {
    if (t < 256) {
#pragma unroll
      for (int q = 0; q < 4; ++q) {
        const int c = k0 + ak + q;
        const float x = tile[(c << 6) + (ar ^ (c & 31))];
        As[ak + q][ar] = __fadd_rn(
            __fmul_rn(__fmul_rn(__fsub_rn(x, mu_a), rs_a), gb[c]), gb[256 + c]);
      }
    }
    const float* brow = Wd1 + (((k0 + bk) << 8) + bc);
    *(float4*)&Bs[bk][bc] = *(const float4*)brow;
    *(float4*)&Bs[bk][bc + 4] = *(const float4*)(brow + 4);
    __syncthreads();
#pragma unroll
    for (int kk = 0; kk < 16; ++kk) {   // k ascending: single FMA chain per (m,c)
      const float4 a0 = *(const float4*)&As[kk][rowT << 3];
      const float4 a1 = *(const float4*)&As[kk][(rowT << 3) + 4];
      const float4 bq = *(const float4*)&Bs[kk][colT << 2];
      const float aa[8] = {a0.x, a0.y, a0.z, a0.w, a1.x, a1.y, a1.z, a1.w};
      const float bbv[4] = {bq.x, bq.y, bq.z, bq.w};
#pragma unroll
      for (int i = 0; i < 8; ++i)
#pragma unroll
        for (int j = 0; j < 4; ++j)
          acc[i][j] = __fmaf_rn(aa[i], bbv[j], acc[i][j]);
    }
    __syncthreads();
  }

  // epilogue: bias + relu -> H[c][m] swizzled (round-0 verbatim; H aliases tile)
  const float4 bd = *(const float4*)(bd1 + (colT << 2));
  const float ba[4] = {bd.x, bd.y, bd.z, bd.w};
#pragma unroll
  for (int i = 0; i < 8; ++i) {
    const int m = (rowT << 3) + i;
#pragma unroll
    for (int j = 0; j < 4; ++j) {
      const int c = (colT << 2) + j;
      H[(c << 6) + (m ^ ((c >> 2) & 31))] = fmaxf(__fadd_rn(acc[i][j], ba[j]), 0.0f);
    }
  }
  __syncthreads();

  // w-chain: ascending-c single FMA chain; key = (w+bd2)/0.1f (round-0 verbatim)
  if (t < 64) {
    float wa = 0.0f;
    for (int c = 0; c < 256; ++c)
      wa = __fmaf_rn(H[(c << 6) + (t ^ ((c >> 2) & 31))], Wd2[c], wa);
    const float w = __fadd_rn(wa, bd2[0]);
    wkey[m0 + t] = __fdiv_rn(w, 0.1f);
  }
}

// ---------------- per-batch top-K: u64-packed bitonic (key desc, tie: lower idx) ----------------
__global__ void __launch_bounds__(1024) topk_kernel(
    const float* __restrict__ wv, const float* __restrict__ xyzs,
    int* __restrict__ idx_out, float* __restrict__ out_xyz,
    float* __restrict__ out_idx) {
  __shared__ unsigned long long vals[2048];
  const int b = blockIdx.x, t = threadIdx.x;
#pragma unroll
  for (int h = 0; h < 2; ++h) {
    const int i = (h << 10) + t;
    const unsigned int u = __float_as_uint(wv[(b << 11) + i]);
    const unsigned int up = ((int)u < 0) ? ~u : (u | 0x80000000u);
    vals[i] = (((unsigned long long)(~up)) << 32) | (unsigned int)i;
  }
  __syncthreads();
  for (int k = 2; k <= 2048; k <<= 1) {
    for (int j = k >> 1; j > 0; j >>= 1) {
      for (int half = 0; half < 2; ++half) {
        const int i = (half << 10) | t;
        const int ixj = i ^ j;
        if (ixj > i) {
          const unsigned long long vi = vals[i], vj = vals[ixj];
          const bool up = ((i & k) == 0);
          if ((vi > vj) == up) { vals[i] = vj; vals[ixj] = vi; }
        }
      }
      __syncthreads();
    }
  }
  const int sel = (int)(vals[t] & 0xffffffffu);
  idx_out[(b << 10) + t] = sel;
  out_idx[(b << 10) + t] = (float)sel;
  const long o = ((long)((b << 10) + t)) * 3;
  const long s3 = ((long)((b << 11) + sel)) * 3;
  out_xyz[o] = xyzs[s3]; out_xyz[o + 1] = xyzs[s3 + 1]; out_xyz[o + 2] = xyzs[s3 + 2];
}

// ---------------- weight prep (merged): W (256x256 f32) -> P bf16 slabs [kc][n][32] ----------------
__global__ __launch_bounds__(256) void prep_w2(const float* __restrict__ W1,
    const float* __restrict__ W2, unsigned short* __restrict__ P1,
    unsigned short* __restrict__ P2) {
  const int g = blockIdx.x;
  const float* W = (g < 8) ? W1 : W2;
  unsigned short* P = (g < 8) ? P1 : P2;
  const int kc = g & 7, n = threadIdx.x;
  unsigned int packed[16];
#pragma unroll
  for (int i = 0; i < 16; ++i) {
    const float a = W[(((kc << 5) + 2 * i) << 8) + n];
    const float bq = W[(((kc << 5) + 2 * i + 1) << 8) + n];
    packed[i] = bf16rne(a) | (bf16rne(bq) << 16);
  }
  uint4* dst = (uint4*)(P + (((kc << 8) + n) << 5));
#pragma unroll
  for (int q = 0; q < 4; ++q)
    dst[q] = make_uint4(packed[4 * q], packed[4 * q + 1], packed[4 * q + 2], packed[4 * q + 3]);
}

// ---------------- fused up-branch: gather -> bf16 MFMA GEMM1(relu) -> GEMM2 -> transposed out ----------------
#define APITCH 264
#define BPITCH 40
__global__ void __launch_bounds__(256) up_mfma(
    const float* __restrict__ fbuf, const int* __restrict__ idxm,
    const unsigned short* __restrict__ Wu1P, const float* __restrict__ bu1,
    const unsigned short* __restrict__ Wu2P, const float* __restrict__ bu2,
    float* __restrict__ out_feat) {
  __shared__ __align__(16) char smem[64 * APITCH * 2 + 256 * BPITCH * 2 + 2048];
  unsigned short* As = (unsigned short*)smem;                       // 33792 B (later Hs)
  unsigned short* Bs = (unsigned short*)(smem + 64 * APITCH * 2);   // 20480 B (later T)
  float* bias1 = (float*)(smem + 64 * APITCH * 2 + 256 * BPITCH * 2);
  float* bias2 = bias1 + 256;
  float* T = (float*)(smem + 64 * APITCH * 2);                      // 64x66 f32 = 16896 B

  const int t = threadIdx.x;
  const int m0 = blockIdx.x << 6;
  const int quad = (t >> 4) & 3, ln = t & 15, w = t >> 6;

  bias1[t] = bu1[t];
  bias2[t] = bu2[t];

  // gather + cvt: As[r][c] bf16, r = t&63, cols (t>>6)*64..+63
  {
    const int r = t & 63, cseg = t >> 6;
    const int m = m0 + r;
    const long srow = (long)(((m >> 10) << 11) + idxm[m]) << 8;
    const float* src = fbuf + srow + (cseg << 6);
    unsigned short* dst = As + r * APITCH + (cseg << 6);
#pragma unroll
    for (int u = 0; u < 16; ++u) {
      const float4 v = *(const float4*)(src + (u << 2));
      const unsigned int lo = bf16rne(v.x) | (bf16rne(v.y) << 16);
      const unsigned int hi = bf16rne(v.z) | (bf16rne(v.w) << 16);
      *(uint2*)(dst + (u << 2)) = make_uint2(lo, hi);
    }
  }

  f32x4 acc[16];
#pragma unroll
  for (int i = 0; i < 16; ++i) acc[i] = (f32x4){0.f, 0.f, 0.f, 0.f};

  // ---- GEMM1: hu = gathered_f @ Wu1 ----
  for (int kc = 0; kc < 8; ++kc) {
    __syncthreads();
    const uint4* sb = (const uint4*)(Wu1P + (((kc << 8) + t) << 5));
    uint4* db = (uint4*)(Bs + t * BPITCH);
    db[0] = sb[0]; db[1] = sb[1]; db[2] = sb[2]; db[3] = sb[3];
    __syncthreads();
    const short8 a = *(const short8*)(As + ((w << 4) + ln) * APITCH + (kc << 5) + (quad << 3));
#pragma unroll
    for (int nt = 0; nt < 16; ++nt) {
      const short8 b = *(const short8*)(Bs + ((nt << 4) + ln) * BPITCH + (quad << 3));
      acc[nt] = __builtin_amdgcn_mfma_f32_16x16x32_bf16(a, b, acc[nt], 0, 0, 0);
    }
  }

  // ---- relu + bias -> Hs (alias As) ----
  __syncthreads();
  unsigned short* Hs = As;
#pragma unroll
  for (int nt = 0; nt < 16; ++nt) {
    const int c = (nt << 4) + ln;
    const float bb = bias1[c];
#pragma unroll
    for (int rr = 0; rr < 4; ++rr) {
      const float h = fmaxf(acc[nt][rr] + bb, 0.0f);
      Hs[((w << 4) + (quad << 2) + rr) * APITCH + c] = (unsigned short)bf16rne(h);
    }
  }
#pragma unroll
  for (int i = 0; i < 16; ++i) acc[i] = (f32x4){0.f, 0.f, 0.f, 0.f};

  // ---- GEMM2: nf = hu @ Wu2 ----
  for (int kc = 0; kc < 8; ++kc) {
    __syncthreads();
    const uint4* sb = (const uint4*)(Wu2P + (((kc << 8) + t) << 5));
    uint4* db = (uint4*)(Bs + t * BPITCH);
    db[0] = sb[0]; db[1] = sb[1]; db[2] = sb[2]; db[3] = sb[3];
    __syncthreads();
    const short8 a = *(const short8*)(Hs + ((w << 4) + ln) * APITCH + (kc << 5) + (quad << 3));
#pragma unroll
    for (int nt = 0; nt < 16; ++nt) {
      const short8 b = *(const short8*)(Bs + ((nt << 4) + ln) * BPITCH + (quad << 3));
      acc[nt] = __builtin_amdgcn_mfma_f32_16x16x32_bf16(a, b, acc[nt], 0, 0, 0);
    }
  }

  // ---- epilogue: +bu2, transpose via LDS, write out_feat (B,C,K) coalesced ----
  const int bb = m0 >> 10, kbase = m0 & 1023;
  for (int ci = 0; ci < 4; ++ci) {
    __syncthreads();
#pragma unroll
    for (int q = 0; q < 4; ++q) {
      const int nt = (ci << 2) + q;
      const int cloc = (q << 4) + ln;
      const float b2 = bias2[(nt << 4) + ln];
#pragma unroll
      for (int rr = 0; rr < 4; ++rr)
        T[cloc * 66 + ((w << 4) + (quad << 2) + rr)] = acc[nt][rr] + b2;
    }
    __syncthreads();
#pragma unroll
    for (int p = 0; p < 16; ++p) {
      const int cl = (p << 2) + (t >> 6);
      const int m = t & 63;
      out_feat[((long)((bb << 8) + (ci << 6) + cl) << 10) + kbase + m] = T[cl * 66 + m];
    }
  }
}

extern "C" void kernel_launch(void* const* d_in, const int* in_sizes, int n_in,
                              void* d_out, int out_size, void* d_ws, size_t ws_size,
                              hipStream_t stream) {
  const float* xyzs     = (const float*)d_in[0];
  const float* features = (const float*)d_in[1];
  const float* ln_gamma = (const float*)d_in[2];
  const float* ln_beta  = (const float*)d_in[3];
  const float* Wu1      = (const float*)d_in[4];
  const float* bu1      = (const float*)d_in[5];
  const float* Wu2      = (const float*)d_in[6];
  const float* bu2      = (const float*)d_in[7];
  const float* Wd1      = (const float*)d_in[8];
  const float* bd1      = (const float*)d_in[9];
  const float* Wd2      = (const float*)d_in[10];
  const float* bd2      = (const float*)d_in[11];

  char* ws = (char*)d_ws;
  float* fbuf = (float*)ws;                              // 16 MB
  unsigned short* Wu1P = (unsigned short*)(ws + 33554432);  // 128 KB bf16 slabs
  unsigned short* Wu2P = (unsigned short*)(ws + 33685504);  // 128 KB
  float* wv   = (float*)(ws + 50331648);                 // 16384 f32
  int*   idx  = (int*)(ws + 50397184);                   // 8192 i32

  float* out_xyz  = (float*)d_out;            // (8,1024,3)
  float* out_feat = out_xyz + 24576;          // (8,256,1024)
  float* out_idx  = out_feat + 2097152;       // (8,1024)

  prep_w2<<<16, 256, 0, stream>>>(Wu1, Wu2, Wu1P, Wu2P);
  ln_wgemm<<<256, 512, 0, stream>>>(features, ln_gamma, ln_beta, fbuf,
                                    Wd1, bd1, Wd2, bd2, wv);
  topk_kernel<<<8, 1024, 0, stream>>>(wv, xyzs, idx, out_xyz, out_idx);
  up_mfma<<<128, 256, 0, stream>>>(fbuf, idx, Wu1P, bu1, Wu2P, bu2, out_feat);
}

// Round 9
// 183.441 us; speedup vs baseline: 1.1608x; 1.0039x over previous
//
#include <hip/hip_runtime.h>

#define B_DIM 8
#define N_DIM 2048
#define C_DIM 256
#define K_SEL 1024

typedef __attribute__((ext_vector_type(8))) short short8;
typedef __attribute__((ext_vector_type(4))) float f32x4;

__device__ __forceinline__ unsigned int bf16rne(float x) {
  unsigned int u = __float_as_uint(x);
  return (u + 0x7fffu + ((u >> 16) & 1u)) >> 16;
}

// ---------------- FUSED LayerNorm + down-GEMM + w-chain: 512 blocks x 256 thr, 32 rows ----------------
// v10: v9's fusion kept, but re-tiled to 32 rows/block so LDS ~54KB -> TWO blocks/CU
// (grid 512 = 2x256 CUs). v7/v9 proved the stall is NOT LDS issue nor A-fetch: it's the
// single-block lock-step barrier structure (all 8 waves drain together, nothing else on
// the CU). Two independent barrier domains let one block compute while the other stages.
// K-loop kept round-0-verbatim in shape (8x4 acc, ascending-k single FMA chain per
// (m,c) -> bit-exact w). Per-row LN chains row-independent -> bit-identical fbuf.
// New thread maps are bank-clean: As-stage ar=t&31 (2-way free), fbuf-write col/thread
// (2-way reads, coalesced stores) -- fixes v9's 1.31M conflicts.
__global__ void __launch_bounds__(256) ln_wgemm(
    const float* __restrict__ feat, const float* __restrict__ gamma,
    const float* __restrict__ beta, float* __restrict__ fbuf,
    const float* __restrict__ Wd1, const float* __restrict__ bd1,
    const float* __restrict__ Wd2, const float* __restrict__ bd2,
    float* __restrict__ wkey) {
  __shared__ __align__(16) float tile[256 * 32];       // 32 KB raw x, [c][m ^ (c&31)]
  __shared__ __align__(16) char smem2[2304 + 16640];   // As 16x36x4 | Bs 16x260x4
  __shared__ float murs[64];                           // mu[0:32], rs[32:64]
  __shared__ float gb[512];                            // gamma[0:256], beta[256:512]
  float (*As)[36] = (float (*)[36])smem2;
  float (*Bs)[260] = (float (*)[260])(smem2 + 2304);
  float* H = tile;                                     // 256x32 f32 = 32 KB alias

  const int t = threadIdx.x;
  const int m0 = blockIdx.x << 5;                      // 32 rows per block
  const int b = m0 >> 11, n0 = m0 & 2047;

  gb[t] = gamma[t];
  gb[256 + t] = beta[t];

  // phase 1: stage raw features (8 passes; wave covers 8 c-rows x 128B contiguous)
  const int cg = t >> 3, nl4 = (t & 7) << 2;           // cg 0..31, nl4 0..28
  for (int pass = 0; pass < 8; ++pass) {
    const int c = (pass << 5) + cg;
    const float4 v = *(const float4*)(feat + (((long)((b << 8) + c)) << 11) + n0 + nl4);
    const int sw = c & 31;
    float* row = tile + (c << 5);
    row[(nl4 + 0) ^ sw] = v.x; row[(nl4 + 1) ^ sw] = v.y;
    row[(nl4 + 2) ^ sw] = v.z; row[(nl4 + 3) ^ sw] = v.w;
  }
  __syncthreads();

  // phase 2: mean/var per row, numpy-bit-exact chains (verbatim, 32-row indexing)
  if (t < 32) {
    float acc = tile[t];
    for (int c = 1; c < 256; ++c) acc = __fadd_rn(acc, tile[(c << 5) + (t ^ (c & 31))]);
    const float mu = __fdiv_rn(acc, 256.0f);

    float pw[2];
#pragma unroll
    for (int blk = 0; blk < 2; ++blk) {
      const int c0 = blk << 7;
      float r8[8];
#pragma unroll
      for (int j = 0; j < 8; ++j) {
        float d = __fsub_rn(tile[((c0 + j) << 5) + (t ^ ((c0 + j) & 31))], mu);
        r8[j] = __fmul_rn(d, d);
      }
      for (int i = 8; i < 128; i += 8) {
#pragma unroll
        for (int j = 0; j < 8; ++j) {
          const int c = c0 + i + j;
          float d = __fsub_rn(tile[(c << 5) + (t ^ (c & 31))], mu);
          r8[j] = __fadd_rn(r8[j], __fmul_rn(d, d));
        }
      }
      pw[blk] = __fadd_rn(__fadd_rn(__fadd_rn(r8[0], r8[1]), __fadd_rn(r8[2], r8[3])),
                          __fadd_rn(__fadd_rn(r8[4], r8[5]), __fadd_rn(r8[6], r8[7])));
    }
    const float var = __fdiv_rn(__fadd_rn(pw[0], pw[1]), 256.0f);
    const float rs = __fdiv_rn(1.0f, __fsqrt_rn(__fadd_rn(var, 1e-6f)));
    murs[t] = mu;
    murs[32 + t] = rs;
  }
  __syncthreads();

  // phase 3: write fbuf. One column per thread: tile reads 2-way (free), stores coalesced.
  // per-element expression identical to verified version.
  {
    const int c = t;
    const float gac = gb[c], bec = gb[256 + c];
    const float* trow = tile + (c << 5);
    const int sw = c & 31;
    for (int r = 0; r < 32; ++r) {
      const float x = trow[r ^ sw];
      const float o = __fadd_rn(
          __fmul_rn(__fmul_rn(__fsub_rn(x, murs[r]), murs[32 + r]), gac), bec);
      fbuf[(((long)(m0 + r)) << 8) + c] = o;
    }
  }
  // no barrier needed: K-loop below only READS tile/murs/gb until its own barriers

  // phase 4: K-loop (round-0 shape verbatim); As staged from tile, normalize folded in
  const int rowT = t >> 6, colT = t & 63;              // rowT 0..3 (uniform per wave)
  const int ar = t & 31, kg4 = (t >> 5) << 2;          // A stagers: t<128, kg4 in {0,4,8,12}
  const int bk = t >> 4, bc = (t & 15) << 4;           // B stagers: all 256, 16 floats each
  const float mu_a = murs[ar], rs_a = murs[32 + ar];
  float acc[8][4] = {};

  for (int k0 = 0; k0 < 256; k0 += 16) {
    if (t < 128) {
#pragma unroll
      for (int q = 0; q < 4; ++q) {
        const int c = k0 + kg4 + q;
        const float x = tile[(c << 5) + (ar ^ (c & 31))];
        As[kg4 + q][ar] = __fadd_rn(
            __fmul_rn(__fmul_rn(__fsub_rn(x, mu_a), rs_a), gb[c]), gb[256 + c]);
      }
    }
    {
      const float* brow = Wd1 + (((k0 + bk) << 8) + bc);
      *(float4*)&Bs[bk][bc]      = *(const float4*)brow;
      *(float4*)&Bs[bk][bc + 4]  = *(const float4*)(brow + 4);
      *(float4*)&Bs[bk][bc + 8]  = *(const float4*)(brow + 8);
      *(float4*)&Bs[bk][bc + 12] = *(const float4*)(brow + 12);
    }
    __syncthreads();
#pragma unroll
    for (int kk = 0; kk < 16; ++kk) {   // k ascending: single FMA chain per (m,c)
      const float4 a0 = *(const float4*)&As[kk][rowT << 3];
      const float4 a1 = *(const float4*)&As[kk][(rowT << 3) + 4];
      const float4 bq = *(const float4*)&Bs[kk][colT << 2];
      const float aa[8] = {a0.x, a0.y, a0.z, a0.w, a1.x, a1.y, a1.z, a1.w};
      const float bbv[4] = {bq.x, bq.y, bq.z, bq.w};
#pragma unroll
      for (int i = 0; i < 8; ++i)
#pragma unroll
        for (int j = 0; j < 4; ++j)
          acc[i][j] = __fmaf_rn(aa[i], bbv[j], acc[i][j]);
    }
    __syncthreads();
  }

  // epilogue: bias + relu -> H[c][m] swizzled (round-0 pattern, 32-row indexing)
  const float4 bd = *(const float4*)(bd1 + (colT << 2));
  const float ba[4] = {bd.x, bd.y, bd.z, bd.w};
#pragma unroll
  for (int i = 0; i < 8; ++i) {
    const int m = (rowT << 3) + i;
#pragma unroll
    for (int j = 0; j < 4; ++j) {
      const int c = (colT << 2) + j;
      H[(c << 5) + (m ^ ((c >> 2) & 31))] = fmaxf(__fadd_rn(acc[i][j], ba[j]), 0.0f);
    }
  }
  __syncthreads();

  // w-chain: ascending-c single FMA chain; key = (w+bd2)/0.1f (verbatim values)
  if (t < 32) {
    float wa = 0.0f;
    for (int c = 0; c < 256; ++c)
      wa = __fmaf_rn(H[(c << 5) + (t ^ ((c >> 2) & 31))], Wd2[c], wa);
    const float w = __fadd_rn(wa, bd2[0]);
    wkey[m0 + t] = __fdiv_rn(w, 0.1f);
  }
}

// ---------------- per-batch top-K: u64-packed bitonic (key desc, tie: lower idx) ----------------
__global__ void __launch_bounds__(1024) topk_kernel(
    const float* __restrict__ wv, const float* __restrict__ xyzs,
    int* __restrict__ idx_out, float* __restrict__ out_xyz,
    float* __restrict__ out_idx) {
  __shared__ unsigned long long vals[2048];
  const int b = blockIdx.x, t = threadIdx.x;
#pragma unroll
  for (int h = 0; h < 2; ++h) {
    const int i = (h << 10) + t;
    const unsigned int u = __float_as_uint(wv[(b << 11) + i]);
    const unsigned int up = ((int)u < 0) ? ~u : (u | 0x80000000u);
    vals[i] = (((unsigned long long)(~up)) << 32) | (unsigned int)i;
  }
  __syncthreads();
  for (int k = 2; k <= 2048; k <<= 1) {
    for (int j = k >> 1; j > 0; j >>= 1) {
      for (int half = 0; half < 2; ++half) {
        const int i = (half << 10) | t;
        const int ixj = i ^ j;
        if (ixj > i) {
          const unsigned long long vi = vals[i], vj = vals[ixj];
          const bool up = ((i & k) == 0);
          if ((vi > vj) == up) { vals[i] = vj; vals[ixj] = vi; }
        }
      }
      __syncthreads();
    }
  }
  const int sel = (int)(vals[t] & 0xffffffffu);
  idx_out[(b << 10) + t] = sel;
  out_idx[(b << 10) + t] = (float)sel;
  const long o = ((long)((b << 10) + t)) * 3;
  const long s3 = ((long)((b << 11) + sel)) * 3;
  out_xyz[o] = xyzs[s3]; out_xyz[o + 1] = xyzs[s3 + 1]; out_xyz[o + 2] = xyzs[s3 + 2];
}

// ---------------- weight prep (merged): W (256x256 f32) -> P bf16 slabs [kc][n][32] ----------------
__global__ __launch_bounds__(256) void prep_w2(const float* __restrict__ W1,
    const float* __restrict__ W2, unsigned short* __restrict__ P1,
    unsigned short* __restrict__ P2) {
  const int g = blockIdx.x;
  const float* W = (g < 8) ? W1 : W2;
  unsigned short* P = (g < 8) ? P1 : P2;
  const int kc = g & 7, n = threadIdx.x;
  unsigned int packed[16];
#pragma unroll
  for (int i = 0; i < 16; ++i) {
    const float a = W[(((kc << 5) + 2 * i) << 8) + n];
    const float bq = W[(((kc << 5) + 2 * i + 1) << 8) + n];
    packed[i] = bf16rne(a) | (bf16rne(bq) << 16);
  }
  uint4* dst = (uint4*)(P + (((kc << 8) + n) << 5));
#pragma unroll
  for (int q = 0; q < 4; ++q)
    dst[q] = make_uint4(packed[4 * q], packed[4 * q + 1], packed[4 * q + 2], packed[4 * q + 3]);
}

// ---------------- fused up-branch: gather -> bf16 MFMA GEMM1(relu) -> GEMM2 -> transposed out ----------------
#define APITCH 264
#define BPITCH 40
__global__ void __launch_bounds__(256) up_mfma(
    const float* __restrict__ fbuf, const int* __restrict__ idxm,
    const unsigned short* __restrict__ Wu1P, const float* __restrict__ bu1,
    const unsigned short* __restrict__ Wu2P, const float* __restrict__ bu2,
    float* __restrict__ out_feat) {
  __shared__ __align__(16) char smem[64 * APITCH * 2 + 256 * BPITCH * 2 + 2048];
  unsigned short* As = (unsigned short*)smem;                       // 33792 B (later Hs)
  unsigned short* Bs = (unsigned short*)(smem + 64 * APITCH * 2);   // 20480 B (later T)
  float* bias1 = (float*)(smem + 64 * APITCH * 2 + 256 * BPITCH * 2);
  float* bias2 = bias1 + 256;
  float* T = (float*)(smem + 64 * APITCH * 2);                      // 64x66 f32 = 16896 B

  const int t = threadIdx.x;
  const int m0 = blockIdx.x << 6;
  const int quad = (t >> 4) & 3, ln = t & 15, w = t >> 6;

  bias1[t] = bu1[t];
  bias2[t] = bu2[t];

  // gather + cvt: As[r][c] bf16, r = t&63, cols (t>>6)*64..+63
  {
    const int r = t & 63, cseg = t >> 6;
    const int m = m0 + r;
    const long srow = (long)(((m >> 10) << 11) + idxm[m]) << 8;
    const float* src = fbuf + srow + (cseg << 6);
    unsigned short* dst = As + r * APITCH + (cseg << 6);
#pragma unroll
    for (int u = 0; u < 16; ++u) {
      const float4 v = *(const float4*)(src + (u << 2));
      const unsigned int lo = bf16rne(v.x) | (bf16rne(v.y) << 16);
      const unsigned int hi = bf16rne(v.z) | (bf16rne(v.w) << 16);
      *(uint2*)(dst + (u << 2)) = make_uint2(lo, hi);
    }
  }

  f32x4 acc[16];
#pragma unroll
  for (int i = 0; i < 16; ++i) acc[i] = (f32x4){0.f, 0.f, 0.f, 0.f};

  // ---- GEMM1: hu = gathered_f @ Wu1 ----
  for (int kc = 0; kc < 8; ++kc) {
    __syncthreads();
    const uint4* sb = (const uint4*)(Wu1P + (((kc << 8) + t) << 5));
    uint4* db = (uint4*)(Bs + t * BPITCH);
    db[0] = sb[0]; db[1] = sb[1]; db[2] = sb[2]; db[3] = sb[3];
    __syncthreads();
    const short8 a = *(const short8*)(As + ((w << 4) + ln) * APITCH + (kc << 5) + (quad << 3));
#pragma unroll
    for (int nt = 0; nt < 16; ++nt) {
      const short8 b = *(const short8*)(Bs + ((nt << 4) + ln) * BPITCH + (quad << 3));
      acc[nt] = __builtin_amdgcn_mfma_f32_16x16x32_bf16(a, b, acc[nt], 0, 0, 0);
    }
  }

  // ---- relu + bias -> Hs (alias As) ----
  __syncthreads();
  unsigned short* Hs = As;
#pragma unroll
  for (int nt = 0; nt < 16; ++nt) {
    const int c = (nt << 4) + ln;
    const float bb = bias1[c];
#pragma unroll
    for (int rr = 0; rr < 4; ++rr) {
      const float h = fmaxf(acc[nt][rr] + bb, 0.0f);
      Hs[((w << 4) + (quad << 2) + rr) * APITCH + c] = (unsigned short)bf16rne(h);
    }
  }
#pragma unroll
  for (int i = 0; i < 16; ++i) acc[i] = (f32x4){0.f, 0.f, 0.f, 0.f};

  // ---- GEMM2: nf = hu @ Wu2 ----
  for (int kc = 0; kc < 8; ++kc) {
    __syncthreads();
    const uint4* sb = (const uint4*)(Wu2P + (((kc << 8) + t) << 5));
    uint4* db = (uint4*)(Bs + t * BPITCH);
    db[0] = sb[0]; db[1] = sb[1]; db[2] = sb[2]; db[3] = sb[3];
    __syncthreads();
    const short8 a = *(const short8*)(Hs + ((w << 4) + ln) * APITCH + (kc << 5) + (quad << 3));
#pragma unroll
    for (int nt = 0; nt < 16; ++nt) {
      const short8 b = *(const short8*)(Bs + ((nt << 4) + ln) * BPITCH + (quad << 3));
      acc[nt] = __builtin_amdgcn_mfma_f32_16x16x32_bf16(a, b, acc[nt], 0, 0, 0);
    }
  }

  // ---- epilogue: +bu2, transpose via LDS, write out_feat (B,C,K) coalesced ----
  const int bb = m0 >> 10, kbase = m0 & 1023;
  for (int ci = 0; ci < 4; ++ci) {
    __syncthreads();
#pragma unroll
    for (int q = 0; q < 4; ++q) {
      const int nt = (ci << 2) + q;
      const int cloc = (q << 4) + ln;
      const float b2 = bias2[(nt << 4) + ln];
#pragma unroll
      for (int rr = 0; rr < 4; ++rr)
        T[cloc * 66 + ((w << 4) + (quad << 2) + rr)] = acc[nt][rr] + b2;
    }
    __syncthreads();
#pragma unroll
    for (int p = 0; p < 16; ++p) {
      const int cl = (p << 2) + (t >> 6);
      const int m = t & 63;
      out_feat[((long)((bb << 8) + (ci << 6) + cl) << 10) + kbase + m] = T[cl * 66 + m];
    }
  }
}

extern "C" void kernel_launch(void* const* d_in, const int* in_sizes, int n_in,
                              void* d_out, int out_size, void* d_ws, size_t ws_size,
                              hipStream_t stream) {
  const float* xyzs     = (const float*)d_in[0];
  const float* features = (const float*)d_in[1];
  const float* ln_gamma = (const float*)d_in[2];
  const float* ln_beta  = (const float*)d_in[3];
  const float* Wu1      = (const float*)d_in[4];
  const float* bu1      = (const float*)d_in[5];
  const float* Wu2      = (const float*)d_in[6];
  const float* bu2      = (const float*)d_in[7];
  const float* Wd1      = (const float*)d_in[8];
  const float* bd1      = (const float*)d_in[9];
  const float* Wd2      = (const float*)d_in[10];
  const float* bd2      = (const float*)d_in[11];

  char* ws = (char*)d_ws;
  float* fbuf = (float*)ws;                              // 16 MB
  unsigned short* Wu1P = (unsigned short*)(ws + 33554432);  // 128 KB bf16 slabs
  unsigned short* Wu2P = (unsigned short*)(ws + 33685504);  // 128 KB
  float* wv   = (float*)(ws + 50331648);                 // 16384 f32
  int*   idx  = (int*)(ws + 50397184);                   // 8192 i32

  float* out_xyz  = (float*)d_out;            // (8,1024,3)
  float* out_feat = out_xyz + 24576;          // (8,256,1024)
  float* out_idx  = out_feat + 2097152;       // (8,1024)

  prep_w2<<<16, 256, 0, stream>>>(Wu1, Wu2, Wu1P, Wu2P);
  ln_wgemm<<<512, 256, 0, stream>>>(features, ln_gamma, ln_beta, fbuf,
                                    Wd1, bd1, Wd2, bd2, wv);
  topk_kernel<<<8, 1024, 0, stream>>>(wv, xyzs, idx, out_xyz, out_idx);
  up_mfma<<<128, 256, 0, stream>>>(fbuf, idx, Wu1P, bu1, Wu2P, bu2, out_feat);
}

// Round 10
// 179.646 us; speedup vs baseline: 1.1853x; 1.0211x over previous
//
#include <hip/hip_runtime.h>

#define B_DIM 8
#define N_DIM 2048
#define C_DIM 256
#define K_SEL 1024

typedef __attribute__((ext_vector_type(8))) short short8;
typedef __attribute__((ext_vector_type(4))) float f32x4;

__device__ __forceinline__ unsigned int bf16rne(float x) {
  unsigned int u = __float_as_uint(x);
  return (u + 0x7fffu + ((u >> 16) & 1u)) >> 16;
}

// ---------------- FUSED LayerNorm + down-GEMM + w-chain: 512 blocks x 256 thr, 32 rows ----------------
// v10 FROZEN: nine K-loop restructures (v2-v8 spill/scalarize/issue-inflate; v9 fusion;
// v10 2-blocks/CU) all failed to move the ~45us GEMM phase. LDS-issue, A-latency and
// block-overlap theories each falsified by measurement; conflicts (0..3.1M) provably
// off the critical path. Keeping the verified bit-exact structure.
__global__ void __launch_bounds__(256) ln_wgemm(
    const float* __restrict__ feat, const float* __restrict__ gamma,
    const float* __restrict__ beta, float* __restrict__ fbuf,
    const float* __restrict__ Wd1, const float* __restrict__ bd1,
    const float* __restrict__ Wd2, const float* __restrict__ bd2,
    float* __restrict__ wkey) {
  __shared__ __align__(16) float tile[256 * 32];       // 32 KB raw x, [c][m ^ (c&31)]
  __shared__ __align__(16) char smem2[2304 + 16640];   // As 16x36x4 | Bs 16x260x4
  __shared__ float murs[64];                           // mu[0:32], rs[32:64]
  __shared__ float gb[512];                            // gamma[0:256], beta[256:512]
  float (*As)[36] = (float (*)[36])smem2;
  float (*Bs)[260] = (float (*)[260])(smem2 + 2304);
  float* H = tile;                                     // 256x32 f32 = 32 KB alias

  const int t = threadIdx.x;
  const int m0 = blockIdx.x << 5;                      // 32 rows per block
  const int b = m0 >> 11, n0 = m0 & 2047;

  gb[t] = gamma[t];
  gb[256 + t] = beta[t];

  // phase 1: stage raw features
  const int cg = t >> 3, nl4 = (t & 7) << 2;           // cg 0..31, nl4 0..28
  for (int pass = 0; pass < 8; ++pass) {
    const int c = (pass << 5) + cg;
    const float4 v = *(const float4*)(feat + (((long)((b << 8) + c)) << 11) + n0 + nl4);
    const int sw = c & 31;
    float* row = tile + (c << 5);
    row[(nl4 + 0) ^ sw] = v.x; row[(nl4 + 1) ^ sw] = v.y;
    row[(nl4 + 2) ^ sw] = v.z; row[(nl4 + 3) ^ sw] = v.w;
  }
  __syncthreads();

  // phase 2: mean/var per row, numpy-bit-exact chains
  if (t < 32) {
    float acc = tile[t];
    for (int c = 1; c < 256; ++c) acc = __fadd_rn(acc, tile[(c << 5) + (t ^ (c & 31))]);
    const float mu = __fdiv_rn(acc, 256.0f);

    float pw[2];
#pragma unroll
    for (int blk = 0; blk < 2; ++blk) {
      const int c0 = blk << 7;
      float r8[8];
#pragma unroll
      for (int j = 0; j < 8; ++j) {
        float d = __fsub_rn(tile[((c0 + j) << 5) + (t ^ ((c0 + j) & 31))], mu);
        r8[j] = __fmul_rn(d, d);
      }
      for (int i = 8; i < 128; i += 8) {
#pragma unroll
        for (int j = 0; j < 8; ++j) {
          const int c = c0 + i + j;
          float d = __fsub_rn(tile[(c << 5) + (t ^ (c & 31))], mu);
          r8[j] = __fadd_rn(r8[j], __fmul_rn(d, d));
        }
      }
      pw[blk] = __fadd_rn(__fadd_rn(__fadd_rn(r8[0], r8[1]), __fadd_rn(r8[2], r8[3])),
                          __fadd_rn(__fadd_rn(r8[4], r8[5]), __fadd_rn(r8[6], r8[7])));
    }
    const float var = __fdiv_rn(__fadd_rn(pw[0], pw[1]), 256.0f);
    const float rs = __fdiv_rn(1.0f, __fsqrt_rn(__fadd_rn(var, 1e-6f)));
    murs[t] = mu;
    murs[32 + t] = rs;
  }
  __syncthreads();

  // phase 3: write fbuf (one column per thread; coalesced stores)
  {
    const int c = t;
    const float gac = gb[c], bec = gb[256 + c];
    const float* trow = tile + (c << 5);
    const int sw = c & 31;
    for (int r = 0; r < 32; ++r) {
      const float x = trow[r ^ sw];
      const float o = __fadd_rn(
          __fmul_rn(__fmul_rn(__fsub_rn(x, murs[r]), murs[32 + r]), gac), bec);
      fbuf[(((long)(m0 + r)) << 8) + c] = o;
    }
  }

  // phase 4: K-loop (round-0 shape); As staged from tile, normalize folded in
  const int rowT = t >> 6, colT = t & 63;
  const int ar = t & 31, kg4 = (t >> 5) << 2;
  const int bk = t >> 4, bc = (t & 15) << 4;
  const float mu_a = murs[ar], rs_a = murs[32 + ar];
  float acc[8][4] = {};

  for (int k0 = 0; k0 < 256; k0 += 16) {
    if (t < 128) {
#pragma unroll
      for (int q = 0; q < 4; ++q) {
        const int c = k0 + kg4 + q;
        const float x = tile[(c << 5) + (ar ^ (c & 31))];
        As[kg4 + q][ar] = __fadd_rn(
            __fmul_rn(__fmul_rn(__fsub_rn(x, mu_a), rs_a), gb[c]), gb[256 + c]);
      }
    }
    {
      const float* brow = Wd1 + (((k0 + bk) << 8) + bc);
      *(float4*)&Bs[bk][bc]      = *(const float4*)brow;
      *(float4*)&Bs[bk][bc + 4]  = *(const float4*)(brow + 4);
      *(float4*)&Bs[bk][bc + 8]  = *(const float4*)(brow + 8);
      *(float4*)&Bs[bk][bc + 12] = *(const float4*)(brow + 12);
    }
    __syncthreads();
#pragma unroll
    for (int kk = 0; kk < 16; ++kk) {   // k ascending: single FMA chain per (m,c)
      const float4 a0 = *(const float4*)&As[kk][rowT << 3];
      const float4 a1 = *(const float4*)&As[kk][(rowT << 3) + 4];
      const float4 bq = *(const float4*)&Bs[kk][colT << 2];
      const float aa[8] = {a0.x, a0.y, a0.z, a0.w, a1.x, a1.y, a1.z, a1.w};
      const float bbv[4] = {bq.x, bq.y, bq.z, bq.w};
#pragma unroll
      for (int i = 0; i < 8; ++i)
#pragma unroll
        for (int j = 0; j < 4; ++j)
          acc[i][j] = __fmaf_rn(aa[i], bbv[j], acc[i][j]);
    }
    __syncthreads();
  }

  // epilogue: bias + relu -> H[c][m] swizzled
  const float4 bd = *(const float4*)(bd1 + (colT << 2));
  const float ba[4] = {bd.x, bd.y, bd.z, bd.w};
#pragma unroll
  for (int i = 0; i < 8; ++i) {
    const int m = (rowT << 3) + i;
#pragma unroll
    for (int j = 0; j < 4; ++j) {
      const int c = (colT << 2) + j;
      H[(c << 5) + (m ^ ((c >> 2) & 31))] = fmaxf(__fadd_rn(acc[i][j], ba[j]), 0.0f);
    }
  }
  __syncthreads();

  // w-chain: ascending-c single FMA chain; key = (w+bd2)/0.1f
  if (t < 32) {
    float wa = 0.0f;
    for (int c = 0; c < 256; ++c)
      wa = __fmaf_rn(H[(c << 5) + (t ^ ((c >> 2) & 31))], Wd2[c], wa);
    const float w = __fadd_rn(wa, bd2[0]);
    wkey[m0 + t] = __fdiv_rn(w, 0.1f);
  }
}

// ---------------- per-batch top-K: u64-packed bitonic (key desc, tie: lower idx) ----------------
__global__ void __launch_bounds__(1024) topk_kernel(
    const float* __restrict__ wv, const float* __restrict__ xyzs,
    int* __restrict__ idx_out, float* __restrict__ out_xyz,
    float* __restrict__ out_idx) {
  __shared__ unsigned long long vals[2048];
  const int b = blockIdx.x, t = threadIdx.x;
#pragma unroll
  for (int h = 0; h < 2; ++h) {
    const int i = (h << 10) + t;
    const unsigned int u = __float_as_uint(wv[(b << 11) + i]);
    const unsigned int up = ((int)u < 0) ? ~u : (u | 0x80000000u);
    vals[i] = (((unsigned long long)(~up)) << 32) | (unsigned int)i;
  }
  __syncthreads();
  for (int k = 2; k <= 2048; k <<= 1) {
    for (int j = k >> 1; j > 0; j >>= 1) {
      for (int half = 0; half < 2; ++half) {
        const int i = (half << 10) | t;
        const int ixj = i ^ j;
        if (ixj > i) {
          const unsigned long long vi = vals[i], vj = vals[ixj];
          const bool up = ((i & k) == 0);
          if ((vi > vj) == up) { vals[i] = vj; vals[ixj] = vi; }
        }
      }
      __syncthreads();
    }
  }
  const int sel = (int)(vals[t] & 0xffffffffu);
  idx_out[(b << 10) + t] = sel;
  out_idx[(b << 10) + t] = (float)sel;
  const long o = ((long)((b << 10) + t)) * 3;
  const long s3 = ((long)((b << 11) + sel)) * 3;
  out_xyz[o] = xyzs[s3]; out_xyz[o + 1] = xyzs[s3 + 1]; out_xyz[o + 2] = xyzs[s3 + 2];
}

// ---------------- weight prep (merged): W (256x256 f32) -> P bf16 slabs [kc][n][32] ----------------
__global__ __launch_bounds__(256) void prep_w2(const float* __restrict__ W1,
    const float* __restrict__ W2, unsigned short* __restrict__ P1,
    unsigned short* __restrict__ P2) {
  const int g = blockIdx.x;
  const float* W = (g < 8) ? W1 : W2;
  unsigned short* P = (g < 8) ? P1 : P2;
  const int kc = g & 7, n = threadIdx.x;
  unsigned int packed[16];
#pragma unroll
  for (int i = 0; i < 16; ++i) {
    const float a = W[(((kc << 5) + 2 * i) << 8) + n];
    const float bq = W[(((kc << 5) + 2 * i + 1) << 8) + n];
    packed[i] = bf16rne(a) | (bf16rne(bq) << 16);
  }
  uint4* dst = (uint4*)(P + (((kc << 8) + n) << 5));
#pragma unroll
  for (int q = 0; q < 4; ++q)
    dst[q] = make_uint4(packed[4 * q], packed[4 * q + 1], packed[4 * q + 2], packed[4 * q + 3]);
}

// ---------------- fused up-branch: 256 blocks x 32 rows (v11: all 256 CUs busy) ----------------
// v11: was 128 blocks x 64 rows -> HALF the CUs idle. Re-tiled: wave w owns row-block
// rb=w>>1 (16 rows) and column-half ch=w&1 (8 tiles). Per-lane MFMA fragment structure
// (quad/ln map, kc order, accumulation order, bf16rne) byte-identical to the verified
// 64-row version -> bit-identical outputs; only tile->wave assignment + epilogue bases
// changed. T is now a separate 64x34 buffer (no aliasing). LDS ~48KB.
#define APITCH 264
#define BPITCH 40
__global__ void __launch_bounds__(256) up_mfma(
    const float* __restrict__ fbuf, const int* __restrict__ idxm,
    const unsigned short* __restrict__ Wu1P, const float* __restrict__ bu1,
    const unsigned short* __restrict__ Wu2P, const float* __restrict__ bu2,
    float* __restrict__ out_feat) {
  __shared__ __align__(16) char smem[32 * APITCH * 2 + 256 * BPITCH * 2 + 64 * 34 * 4 + 2048];
  unsigned short* As = (unsigned short*)smem;                       // 16896 B (later Hs)
  unsigned short* Bs = (unsigned short*)(smem + 32 * APITCH * 2);   // 20480 B
  float* T = (float*)(smem + 32 * APITCH * 2 + 256 * BPITCH * 2);   // 64x34 f32 = 8704 B
  float* bias1 = (float*)(smem + 32 * APITCH * 2 + 256 * BPITCH * 2 + 64 * 34 * 4);
  float* bias2 = bias1 + 256;

  const int t = threadIdx.x;
  const int m0 = blockIdx.x << 5;                      // 32 rows per block
  const int quad = (t >> 4) & 3, ln = t & 15, w = t >> 6;
  const int rb = w >> 1, ch = w & 1;

  bias1[t] = bu1[t];
  bias2[t] = bu2[t];

  // gather + cvt: As[r][c] bf16, r = t&31, cols (t>>5)*32..+32
  {
    const int r = t & 31, cseg = t >> 5;
    const int m = m0 + r;
    const long srow = (long)(((m >> 10) << 11) + idxm[m]) << 8;
    const float* src = fbuf + srow + (cseg << 5);
    unsigned short* dst = As + r * APITCH + (cseg << 5);
#pragma unroll
    for (int u = 0; u < 8; ++u) {
      const float4 v = *(const float4*)(src + (u << 2));
      const unsigned int lo = bf16rne(v.x) | (bf16rne(v.y) << 16);
      const unsigned int hi = bf16rne(v.z) | (bf16rne(v.w) << 16);
      *(uint2*)(dst + (u << 2)) = make_uint2(lo, hi);
    }
  }

  f32x4 acc[8];
#pragma unroll
  for (int i = 0; i < 8; ++i) acc[i] = (f32x4){0.f, 0.f, 0.f, 0.f};

  // ---- GEMM1: hu = gathered_f @ Wu1 ----
  for (int kc = 0; kc < 8; ++kc) {
    __syncthreads();
    const uint4* sb = (const uint4*)(Wu1P + (((kc << 8) + t) << 5));
    uint4* db = (uint4*)(Bs + t * BPITCH);
    db[0] = sb[0]; db[1] = sb[1]; db[2] = sb[2]; db[3] = sb[3];
    __syncthreads();
    const short8 a = *(const short8*)(As + ((rb << 4) + ln) * APITCH + (kc << 5) + (quad << 3));
#pragma unroll
    for (int nt = 0; nt < 8; ++nt) {
      const int ntg = (ch << 3) + nt;
      const short8 b = *(const short8*)(Bs + ((ntg << 4) + ln) * BPITCH + (quad << 3));
      acc[nt] = __builtin_amdgcn_mfma_f32_16x16x32_bf16(a, b, acc[nt], 0, 0, 0);
    }
  }

  // ---- relu + bias -> Hs (alias As) ----
  __syncthreads();
  unsigned short* Hs = As;
#pragma unroll
  for (int nt = 0; nt < 8; ++nt) {
    const int c = ((ch << 3) + nt << 4) + ln;
    const float bb = bias1[c];
#pragma unroll
    for (int rr = 0; rr < 4; ++rr) {
      const float h = fmaxf(acc[nt][rr] + bb, 0.0f);
      Hs[((rb << 4) + (quad << 2) + rr) * APITCH + c] = (unsigned short)bf16rne(h);
    }
  }
#pragma unroll
  for (int i = 0; i < 8; ++i) acc[i] = (f32x4){0.f, 0.f, 0.f, 0.f};

  // ---- GEMM2: nf = hu @ Wu2 ----
  for (int kc = 0; kc < 8; ++kc) {
    __syncthreads();
    const uint4* sb = (const uint4*)(Wu2P + (((kc << 8) + t) << 5));
    uint4* db = (uint4*)(Bs + t * BPITCH);
    db[0] = sb[0]; db[1] = sb[1]; db[2] = sb[2]; db[3] = sb[3];
    __syncthreads();
    const short8 a = *(const short8*)(Hs + ((rb << 4) + ln) * APITCH + (kc << 5) + (quad << 3));
#pragma unroll
    for (int nt = 0; nt < 8; ++nt) {
      const int ntg = (ch << 3) + nt;
      const short8 b = *(const short8*)(Bs + ((ntg << 4) + ln) * BPITCH + (quad << 3));
      acc[nt] = __builtin_amdgcn_mfma_f32_16x16x32_bf16(a, b, acc[nt], 0, 0, 0);
    }
  }

  // ---- epilogue: +bu2, transpose via T, write out_feat (B,C,K) coalesced ----
  const int bb = m0 >> 10, kbase = m0 & 1023;
  for (int ci = 0; ci < 4; ++ci) {
    __syncthreads();
    if ((ci >> 1) == ch) {
#pragma unroll
      for (int q = 0; q < 4; ++q) {
        const int nt = ((ci & 1) << 2) + q;            // local tile index in this wave
        const int cloc = (q << 4) + ln;                // col within the 64-col group
        const float b2 = bias2[(ci << 6) + cloc];
        const int row = (rb << 4) + (quad << 2);
#pragma unroll
        for (int rr = 0; rr < 4; ++rr)
          T[cloc * 34 + row + rr] = acc[nt][rr] + b2;
      }
    }
    __syncthreads();
#pragma unroll
    for (int p = 0; p < 8; ++p) {
      const int cl = (p << 3) + (t >> 5);
      const int m = t & 31;
      out_feat[((long)((bb << 8) + (ci << 6) + cl) << 10) + kbase + m] = T[cl * 34 + m];
    }
  }
}

extern "C" void kernel_launch(void* const* d_in, const int* in_sizes, int n_in,
                              void* d_out, int out_size, void* d_ws, size_t ws_size,
                              hipStream_t stream) {
  const float* xyzs     = (const float*)d_in[0];
  const float* features = (const float*)d_in[1];
  const float* ln_gamma = (const float*)d_in[2];
  const float* ln_beta  = (const float*)d_in[3];
  const float* Wu1      = (const float*)d_in[4];
  const float* bu1      = (const float*)d_in[5];
  const float* Wu2      = (const float*)d_in[6];
  const float* bu2      = (const float*)d_in[7];
  const float* Wd1      = (const float*)d_in[8];
  const float* bd1      = (const float*)d_in[9];
  const float* Wd2      = (const float*)d_in[10];
  const float* bd2      = (const float*)d_in[11];

  char* ws = (char*)d_ws;
  float* fbuf = (float*)ws;                              // 16 MB
  unsigned short* Wu1P = (unsigned short*)(ws + 33554432);  // 128 KB bf16 slabs
  unsigned short* Wu2P = (unsigned short*)(ws + 33685504);  // 128 KB
  float* wv   = (float*)(ws + 50331648);                 // 16384 f32
  int*   idx  = (int*)(ws + 50397184);                   // 8192 i32

  float* out_xyz  = (float*)d_out;            // (8,1024,3)
  float* out_feat = out_xyz + 24576;          // (8,256,1024)
  float* out_idx  = out_feat + 2097152;       // (8,1024)

  prep_w2<<<16, 256, 0, stream>>>(Wu1, Wu2, Wu1P, Wu2P);
  ln_wgemm<<<512, 256, 0, stream>>>(features, ln_gamma, ln_beta, fbuf,
                                    Wd1, bd1, Wd2, bd2, wv);
  topk_kernel<<<8, 1024, 0, stream>>>(wv, xyzs, idx, out_xyz, out_idx);
  up_mfma<<<256, 256, 0, stream>>>(fbuf, idx, Wu1P, bu1, Wu2P, bu2, out_feat);
}

// Round 11
// 170.577 us; speedup vs baseline: 1.2484x; 1.0532x over previous
//
#include <hip/hip_runtime.h>

#define B_DIM 8
#define N_DIM 2048
#define C_DIM 256
#define K_SEL 1024

typedef __attribute__((ext_vector_type(8))) short short8;
typedef __attribute__((ext_vector_type(4))) float f32x4;

__device__ __forceinline__ unsigned int bf16rne(float x) {
  unsigned int u = __float_as_uint(x);
  return (u + 0x7fffu + ((u >> 16) & 1u)) >> 16;
}

// ---------------- FUSED LayerNorm + down-GEMM + w-chain (+ prep_w2 tail blocks) ----------------
// v10 structure FROZEN (nine K-loop restructures failed; see journal). v12 adds 16 tail
// blocks (blockIdx >= 512) that run the verbatim prep_w2 body -> one fewer launch.
__global__ void __launch_bounds__(256) ln_wgemm(
    const float* __restrict__ feat, const float* __restrict__ gamma,
    const float* __restrict__ beta, float* __restrict__ fbuf,
    const float* __restrict__ Wd1, const float* __restrict__ bd1,
    const float* __restrict__ Wd2, const float* __restrict__ bd2,
    float* __restrict__ wkey,
    const float* __restrict__ Wu1, const float* __restrict__ Wu2,
    unsigned short* __restrict__ Wu1P, unsigned short* __restrict__ Wu2P) {
  __shared__ __align__(16) float tile[256 * 32];       // 32 KB raw x, [c][m ^ (c&31)]
  __shared__ __align__(16) char smem2[2304 + 16640];   // As 16x36x4 | Bs 16x260x4
  __shared__ float murs[64];                           // mu[0:32], rs[32:64]
  __shared__ float gb[512];                            // gamma[0:256], beta[256:512]
  float (*As)[36] = (float (*)[36])smem2;
  float (*Bs)[260] = (float (*)[260])(smem2 + 2304);
  float* H = tile;                                     // 256x32 f32 = 32 KB alias

  const int t = threadIdx.x;

  // ---- prep_w2 tail blocks (verbatim body; independent of LN work) ----
  if (blockIdx.x >= 512) {
    const int g = blockIdx.x - 512;
    const float* W = (g < 8) ? Wu1 : Wu2;
    unsigned short* P = (g < 8) ? Wu1P : Wu2P;
    const int kc = g & 7, n = t;
    unsigned int packed[16];
#pragma unroll
    for (int i = 0; i < 16; ++i) {
      const float a = W[(((kc << 5) + 2 * i) << 8) + n];
      const float bq = W[(((kc << 5) + 2 * i + 1) << 8) + n];
      packed[i] = bf16rne(a) | (bf16rne(bq) << 16);
    }
    uint4* dst = (uint4*)(P + (((kc << 8) + n) << 5));
#pragma unroll
    for (int q = 0; q < 4; ++q)
      dst[q] = make_uint4(packed[4 * q], packed[4 * q + 1], packed[4 * q + 2], packed[4 * q + 3]);
    return;
  }

  const int m0 = blockIdx.x << 5;                      // 32 rows per block
  const int b = m0 >> 11, n0 = m0 & 2047;

  gb[t] = gamma[t];
  gb[256 + t] = beta[t];

  // phase 1: stage raw features
  const int cg = t >> 3, nl4 = (t & 7) << 2;           // cg 0..31, nl4 0..28
  for (int pass = 0; pass < 8; ++pass) {
    const int c = (pass << 5) + cg;
    const float4 v = *(const float4*)(feat + (((long)((b << 8) + c)) << 11) + n0 + nl4);
    const int sw = c & 31;
    float* row = tile + (c << 5);
    row[(nl4 + 0) ^ sw] = v.x; row[(nl4 + 1) ^ sw] = v.y;
    row[(nl4 + 2) ^ sw] = v.z; row[(nl4 + 3) ^ sw] = v.w;
  }
  __syncthreads();

  // phase 2: mean/var per row, numpy-bit-exact chains
  if (t < 32) {
    float acc = tile[t];
    for (int c = 1; c < 256; ++c) acc = __fadd_rn(acc, tile[(c << 5) + (t ^ (c & 31))]);
    const float mu = __fdiv_rn(acc, 256.0f);

    float pw[2];
#pragma unroll
    for (int blk = 0; blk < 2; ++blk) {
      const int c0 = blk << 7;
      float r8[8];
#pragma unroll
      for (int j = 0; j < 8; ++j) {
        float d = __fsub_rn(tile[((c0 + j) << 5) + (t ^ ((c0 + j) & 31))], mu);
        r8[j] = __fmul_rn(d, d);
      }
      for (int i = 8; i < 128; i += 8) {
#pragma unroll
        for (int j = 0; j < 8; ++j) {
          const int c = c0 + i + j;
          float d = __fsub_rn(tile[(c << 5) + (t ^ (c & 31))], mu);
          r8[j] = __fadd_rn(r8[j], __fmul_rn(d, d));
        }
      }
      pw[blk] = __fadd_rn(__fadd_rn(__fadd_rn(r8[0], r8[1]), __fadd_rn(r8[2], r8[3])),
                          __fadd_rn(__fadd_rn(r8[4], r8[5]), __fadd_rn(r8[6], r8[7])));
    }
    const float var = __fdiv_rn(__fadd_rn(pw[0], pw[1]), 256.0f);
    const float rs = __fdiv_rn(1.0f, __fsqrt_rn(__fadd_rn(var, 1e-6f)));
    murs[t] = mu;
    murs[32 + t] = rs;
  }
  __syncthreads();

  // phase 3: write fbuf (one column per thread; coalesced stores)
  {
    const int c = t;
    const float gac = gb[c], bec = gb[256 + c];
    const float* trow = tile + (c << 5);
    const int sw = c & 31;
    for (int r = 0; r < 32; ++r) {
      const float x = trow[r ^ sw];
      const float o = __fadd_rn(
          __fmul_rn(__fmul_rn(__fsub_rn(x, murs[r]), murs[32 + r]), gac), bec);
      fbuf[(((long)(m0 + r)) << 8) + c] = o;
    }
  }

  // phase 4: K-loop (round-0 shape); As staged from tile, normalize folded in
  const int rowT = t >> 6, colT = t & 63;
  const int ar = t & 31, kg4 = (t >> 5) << 2;
  const int bk = t >> 4, bc = (t & 15) << 4;
  const float mu_a = murs[ar], rs_a = murs[32 + ar];
  float acc[8][4] = {};

  for (int k0 = 0; k0 < 256; k0 += 16) {
    if (t < 128) {
#pragma unroll
      for (int q = 0; q < 4; ++q) {
        const int c = k0 + kg4 + q;
        const float x = tile[(c << 5) + (ar ^ (c & 31))];
        As[kg4 + q][ar] = __fadd_rn(
            __fmul_rn(__fmul_rn(__fsub_rn(x, mu_a), rs_a), gb[c]), gb[256 + c]);
      }
    }
    {
      const float* brow = Wd1 + (((k0 + bk) << 8) + bc);
      *(float4*)&Bs[bk][bc]      = *(const float4*)brow;
      *(float4*)&Bs[bk][bc + 4]  = *(const float4*)(brow + 4);
      *(float4*)&Bs[bk][bc + 8]  = *(const float4*)(brow + 8);
      *(float4*)&Bs[bk][bc + 12] = *(const float4*)(brow + 12);
    }
    __syncthreads();
#pragma unroll
    for (int kk = 0; kk < 16; ++kk) {   // k ascending: single FMA chain per (m,c)
      const float4 a0 = *(const float4*)&As[kk][rowT << 3];
      const float4 a1 = *(const float4*)&As[kk][(rowT << 3) + 4];
      const float4 bq = *(const float4*)&Bs[kk][colT << 2];
      const float aa[8] = {a0.x, a0.y, a0.z, a0.w, a1.x, a1.y, a1.z, a1.w};
      const float bbv[4] = {bq.x, bq.y, bq.z, bq.w};
#pragma unroll
      for (int i = 0; i < 8; ++i)
#pragma unroll
        for (int j = 0; j < 4; ++j)
          acc[i][j] = __fmaf_rn(aa[i], bbv[j], acc[i][j]);
    }
    __syncthreads();
  }

  // epilogue: bias + relu -> H[c][m] swizzled
  const float4 bd = *(const float4*)(bd1 + (colT << 2));
  const float ba[4] = {bd.x, bd.y, bd.z, bd.w};
#pragma unroll
  for (int i = 0; i < 8; ++i) {
    const int m = (rowT << 3) + i;
#pragma unroll
    for (int j = 0; j < 4; ++j) {
      const int c = (colT << 2) + j;
      H[(c << 5) + (m ^ ((c >> 2) & 31))] = fmaxf(__fadd_rn(acc[i][j], ba[j]), 0.0f);
    }
  }
  __syncthreads();

  // w-chain: ascending-c single FMA chain; key = (w+bd2)/0.1f
  if (t < 32) {
    float wa = 0.0f;
    for (int c = 0; c < 256; ++c)
      wa = __fmaf_rn(H[(c << 5) + (t ^ ((c >> 2) & 31))], Wd2[c], wa);
    const float w = __fadd_rn(wa, bd2[0]);
    wkey[m0 + t] = __fdiv_rn(w, 0.1f);
  }
}

// ---------------- per-batch top-K: register+shuffle bitonic ----------------
// v12: was LDS bitonic with 66 block-wide barriers on 8 blocks (latency chain on 3% of
// the chip). Now thread t holds elements 2t,2t+1 in REGISTERS: j=1 in-thread; j=2..64
// via __shfl_xor (lane mask j/2 <= 32, intra-wave, no barrier); only j in {128,256,512,
// 1024} (10 of 66 stages) go through LDS (2 barriers each -> 20 barriers total).
// Keys are distinct u64 (index in low bits) -> any correct ascending sort yields the
// bit-identical permutation of the verified LDS version -> outputs unchanged.
__global__ void __launch_bounds__(1024) topk_kernel(
    const float* __restrict__ wv, const float* __restrict__ xyzs,
    int* __restrict__ idx_out, float* __restrict__ out_xyz,
    float* __restrict__ out_idx) {
  __shared__ unsigned long long vals[2048];
  const int b = blockIdx.x, t = threadIdx.x;

  unsigned long long a0, a1;
  {
    const float2 w2 = *(const float2*)(wv + (b << 11) + (t << 1));
    const unsigned int u0 = __float_as_uint(w2.x);
    const unsigned int p0 = ((int)u0 < 0) ? ~u0 : (u0 | 0x80000000u);
    a0 = (((unsigned long long)(~p0)) << 32) | (unsigned int)(2 * t);
    const unsigned int u1 = __float_as_uint(w2.y);
    const unsigned int p1 = ((int)u1 < 0) ? ~u1 : (u1 | 0x80000000u);
    a1 = (((unsigned long long)(~p1)) << 32) | (unsigned int)(2 * t + 1);
  }

  for (int k = 2; k <= 2048; k <<= 1) {
    for (int j = k >> 1; j >= 2; j >>= 1) {
      const int x = j >> 1;                       // partner-thread xor distance
      const bool up = (((t << 1) & k) == 0);      // (2t)&k == (2t+1)&k since k >= 4
      unsigned long long p0, p1;
      if (j >= 128) {                             // cross-wave: via LDS
        vals[2 * t] = a0; vals[2 * t + 1] = a1;
        __syncthreads();
        p0 = vals[(2 * t) ^ j];
        p1 = vals[(2 * t + 1) ^ j];
        __syncthreads();                          // WAR guard for next LDS stage
      } else {                                    // intra-wave: x <= 32
        p0 = __shfl_xor(a0, x, 64);
        p1 = __shfl_xor(a1, x, 64);
      }
      const bool lower = ((t & x) == 0);
      const bool take_min = (lower == up);
      a0 = take_min ? (a0 < p0 ? a0 : p0) : (a0 > p0 ? a0 : p0);
      a1 = take_min ? (a1 < p1 ? a1 : p1) : (a1 > p1 ? a1 : p1);
    }
    // j == 1: within-thread pair (2t, 2t+1)
    {
      const bool up1 = (((t << 1) & k) == 0);
      if ((a0 > a1) == up1) { const unsigned long long tmp = a0; a0 = a1; a1 = tmp; }
    }
  }

  // ascending full sort in blocked layout: thread t holds ranks 2t, 2t+1
  if (t < 512) {
    const int r0 = 2 * t, r1 = 2 * t + 1;
    const int s0 = (int)(a0 & 0xffffffffu);
    const int s1 = (int)(a1 & 0xffffffffu);
    idx_out[(b << 10) + r0] = s0;
    idx_out[(b << 10) + r1] = s1;
    out_idx[(b << 10) + r0] = (float)s0;
    out_idx[(b << 10) + r1] = (float)s1;
    const long o0 = ((long)((b << 10) + r0)) * 3;
    const long q0 = ((long)((b << 11) + s0)) * 3;
    out_xyz[o0] = xyzs[q0]; out_xyz[o0 + 1] = xyzs[q0 + 1]; out_xyz[o0 + 2] = xyzs[q0 + 2];
    const long o1 = ((long)((b << 10) + r1)) * 3;
    const long q1 = ((long)((b << 11) + s1)) * 3;
    out_xyz[o1] = xyzs[q1]; out_xyz[o1 + 1] = xyzs[q1 + 1]; out_xyz[o1 + 2] = xyzs[q1 + 2];
  }
}

// ---------------- fused up-branch: 256 blocks x 32 rows (v11, verified) ----------------
#define APITCH 264
#define BPITCH 40
__global__ void __launch_bounds__(256) up_mfma(
    const float* __restrict__ fbuf, const int* __restrict__ idxm,
    const unsigned short* __restrict__ Wu1P, const float* __restrict__ bu1,
    const unsigned short* __restrict__ Wu2P, const float* __restrict__ bu2,
    float* __restrict__ out_feat) {
  __shared__ __align__(16) char smem[32 * APITCH * 2 + 256 * BPITCH * 2 + 64 * 34 * 4 + 2048];
  unsigned short* As = (unsigned short*)smem;                       // 16896 B (later Hs)
  unsigned short* Bs = (unsigned short*)(smem + 32 * APITCH * 2);   // 20480 B
  float* T = (float*)(smem + 32 * APITCH * 2 + 256 * BPITCH * 2);   // 64x34 f32 = 8704 B
  float* bias1 = (float*)(smem + 32 * APITCH * 2 + 256 * BPITCH * 2 + 64 * 34 * 4);
  float* bias2 = bias1 + 256;

  const int t = threadIdx.x;
  const int m0 = blockIdx.x << 5;                      // 32 rows per block
  const int quad = (t >> 4) & 3, ln = t & 15, w = t >> 6;
  const int rb = w >> 1, ch = w & 1;

  bias1[t] = bu1[t];
  bias2[t] = bu2[t];

  // gather + cvt: As[r][c] bf16, r = t&31, cols (t>>5)*32..+32
  {
    const int r = t & 31, cseg = t >> 5;
    const int m = m0 + r;
    const long srow = (long)(((m >> 10) << 11) + idxm[m]) << 8;
    const float* src = fbuf + srow + (cseg << 5);
    unsigned short* dst = As + r * APITCH + (cseg << 5);
#pragma unroll
    for (int u = 0; u < 8; ++u) {
      const float4 v = *(const float4*)(src + (u << 2));
      const unsigned int lo = bf16rne(v.x) | (bf16rne(v.y) << 16);
      const unsigned int hi = bf16rne(v.z) | (bf16rne(v.w) << 16);
      *(uint2*)(dst + (u << 2)) = make_uint2(lo, hi);
    }
  }

  f32x4 acc[8];
#pragma unroll
  for (int i = 0; i < 8; ++i) acc[i] = (f32x4){0.f, 0.f, 0.f, 0.f};

  // ---- GEMM1: hu = gathered_f @ Wu1 ----
  for (int kc = 0; kc < 8; ++kc) {
    __syncthreads();
    const uint4* sb = (const uint4*)(Wu1P + (((kc << 8) + t) << 5));
    uint4* db = (uint4*)(Bs + t * BPITCH);
    db[0] = sb[0]; db[1] = sb[1]; db[2] = sb[2]; db[3] = sb[3];
    __syncthreads();
    const short8 a = *(const short8*)(As + ((rb << 4) + ln) * APITCH + (kc << 5) + (quad << 3));
#pragma unroll
    for (int nt = 0; nt < 8; ++nt) {
      const int ntg = (ch << 3) + nt;
      const short8 b = *(const short8*)(Bs + ((ntg << 4) + ln) * BPITCH + (quad << 3));
      acc[nt] = __builtin_amdgcn_mfma_f32_16x16x32_bf16(a, b, acc[nt], 0, 0, 0);
    }
  }

  // ---- relu + bias -> Hs (alias As) ----
  __syncthreads();
  unsigned short* Hs = As;
#pragma unroll
  for (int nt = 0; nt < 8; ++nt) {
    const int c = ((ch << 3) + nt << 4) + ln;
    const float bb = bias1[c];
#pragma unroll
    for (int rr = 0; rr < 4; ++rr) {
      const float h = fmaxf(acc[nt][rr] + bb, 0.0f);
      Hs[((rb << 4) + (quad << 2) + rr) * APITCH + c] = (unsigned short)bf16rne(h);
    }
  }
#pragma unroll
  for (int i = 0; i < 8; ++i) acc[i] = (f32x4){0.f, 0.f, 0.f, 0.f};

  // ---- GEMM2: nf = hu @ Wu2 ----
  for (int kc = 0; kc < 8; ++kc) {
    __syncthreads();
    const uint4* sb = (const uint4*)(Wu2P + (((kc << 8) + t) << 5));
    uint4* db = (uint4*)(Bs + t * BPITCH);
    db[0] = sb[0]; db[1] = sb[1]; db[2] = sb[2]; db[3] = sb[3];
    __syncthreads();
    const short8 a = *(const short8*)(Hs + ((rb << 4) + ln) * APITCH + (kc << 5) + (quad << 3));
#pragma unroll
    for (int nt = 0; nt < 8; ++nt) {
      const int ntg = (ch << 3) + nt;
      const short8 b = *(const short8*)(Bs + ((ntg << 4) + ln) * BPITCH + (quad << 3));
      acc[nt] = __builtin_amdgcn_mfma_f32_16x16x32_bf16(a, b, acc[nt], 0, 0, 0);
    }
  }

  // ---- epilogue: +bu2, transpose via T, write out_feat (B,C,K) coalesced ----
  const int bb = m0 >> 10, kbase = m0 & 1023;
  for (int ci = 0; ci < 4; ++ci) {
    __syncthreads();
    if ((ci >> 1) == ch) {
#pragma unroll
      for (int q = 0; q < 4; ++q) {
        const int nt = ((ci & 1) << 2) + q;            // local tile index in this wave
        const int cloc = (q << 4) + ln;                // col within the 64-col group
        const float b2 = bias2[(ci << 6) + cloc];
        const int row = (rb << 4) + (quad << 2);
#pragma unroll
        for (int rr = 0; rr < 4; ++rr)
          T[cloc * 34 + row + rr] = acc[nt][rr] + b2;
      }
    }
    __syncthreads();
#pragma unroll
    for (int p = 0; p < 8; ++p) {
      const int cl = (p << 3) + (t >> 5);
      const int m = t & 31;
      out_feat[((long)((bb << 8) + (ci << 6) + cl) << 10) + kbase + m] = T[cl * 34 + m];
    }
  }
}

extern "C" void kernel_launch(void* const* d_in, const int* in_sizes, int n_in,
                              void* d_out, int out_size, void* d_ws, size_t ws_size,
                              hipStream_t stream) {
  const float* xyzs     = (const float*)d_in[0];
  const float* features = (const float*)d_in[1];
  const float* ln_gamma = (const float*)d_in[2];
  const float* ln_beta  = (const float*)d_in[3];
  const float* Wu1      = (const float*)d_in[4];
  const float* bu1      = (const float*)d_in[5];
  const float* Wu2      = (const float*)d_in[6];
  const float* bu2      = (const float*)d_in[7];
  const float* Wd1      = (const float*)d_in[8];
  const float* bd1      = (const float*)d_in[9];
  const float* Wd2      = (const float*)d_in[10];
  const float* bd2      = (const float*)d_in[11];

  char* ws = (char*)d_ws;
  float* fbuf = (float*)ws;                              // 16 MB
  unsigned short* Wu1P = (unsigned short*)(ws + 33554432);  // 128 KB bf16 slabs
  unsigned short* Wu2P = (unsigned short*)(ws + 33685504);  // 128 KB
  float* wv   = (float*)(ws + 50331648);                 // 16384 f32
  int*   idx  = (int*)(ws + 50397184);                   // 8192 i32

  float* out_xyz  = (float*)d_out;            // (8,1024,3)
  float* out_feat = out_xyz + 24576;          // (8,256,1024)
  float* out_idx  = out_feat + 2097152;       // (8,1024)

  ln_wgemm<<<528, 256, 0, stream>>>(features, ln_gamma, ln_beta, fbuf,
                                    Wd1, bd1, Wd2, bd2, wv,
                                    Wu1, Wu2, Wu1P, Wu2P);
  topk_kernel<<<8, 1024, 0, stream>>>(wv, xyzs, idx, out_xyz, out_idx);
  up_mfma<<<256, 256, 0, stream>>>(fbuf, idx, Wu1P, bu1, Wu2P, bu2, out_feat);
}